// Round 5
// baseline (313.052 us; speedup 1.0000x reference)
//
#include <hip/hip_runtime.h>

// GestureRNN v13: v12 MFMA core, restructured for ONE latency exposure/step.
// B=4096, T=512, IN=10, H=32, NCLS=9.
//
// v12 post-mortem (220us, MfmaUtil 4.5%, VALUBusy 10%, occ 2.97% = 1 wave/CU):
// latency-stall-bound. In-order issue + 3-4 dependent-MFMA stalls per step
// (d0b=MFMA(..,d0a) accumulate chain; cvt right after its producing MFMA),
// nothing co-resident to hide them. v13:
//  (1) layer-pipelined step (computes h1[tau], h2[tau-1]) so layer-1 MFMAs
//      read the OLD h1f -> no intra-step MFMA->MFMA dep;
//  (2) h2 accumulation split into d=MFMA(W_ih1,h1f,b1) and e=MFMA(W_hh1,h2f,0)
//      with VALU adds -> all 6 step MFMAs mutually independent;
//  (3) loop-carried chains: h1f->MFMA->cvt->h1f, h2f->MFMA->add->cvt->h2f.
// Layout conjugation (K(k)=16*((k>>2)&1)+4*(k>>3)+(k&3)) verified on HW in
// v12 (absmax identical to scalar version). xproj per-chunk MFMA phase with
// f32-accurate 3-term split; biases in C-init. 1 wave/block, 256 blocks.

constexpr int T_  = 512;
constexpr int IN_ = 10;
constexpr int H_  = 32;
constexpr int NC_ = 9;
constexpr int CT_ = 16;        // timesteps per chunk
constexpr int NCH = T_ / CT_;  // 32 chunks
constexpr int XP_ = 20;        // padded floats per (slot,lane) in xlds

typedef _Float16 f16x8 __attribute__((ext_vector_type(8)));
typedef float    f32x4 __attribute__((ext_vector_type(4)));

__device__ __forceinline__ void cfence() { __asm__ volatile("" ::: "memory"); }

__device__ __forceinline__ f32x4 MFMA(f16x8 a, f16x8 b, f32x4 c) {
    return __builtin_amdgcn_mfma_f32_16x16x32_f16(a, b, c, 0, 0, 0);
}

__global__ __launch_bounds__(64, 1) void gesture_rnn_kernel(
    const float* __restrict__ x,      // [B, T, IN]
    const float* __restrict__ W_ih0,  // [H, IN]
    const float* __restrict__ W_hh0,  // [H, H]
    const float* __restrict__ b_ih0,  // [H]
    const float* __restrict__ b_hh0,  // [H]
    const float* __restrict__ W_ih1,  // [H, H]
    const float* __restrict__ W_hh1,  // [H, H]
    const float* __restrict__ b_ih1,  // [H]
    const float* __restrict__ b_hh1,  // [H]
    const float* __restrict__ W_fc,   // [NC, H]
    const float* __restrict__ b_fc,   // [NC]
    float* __restrict__ out)          // [B, NC]
{
    const int lane = threadIdx.x;     // 0..63
    const int c    = lane & 15;       // batch slot (B/C col, A row)
    const int g    = lane >> 4;       // k-group (A/B), C row-group
    const long b   = (long)blockIdx.x * 16 + c;

    // ---- A-fragments. Lane l: row = l&15, k = (l>>4)*8 + j.
    //      Recurrent matrices use k-order K(k); xproj uses natural k. ----
    f16x8 ah0[2], ai1[2], ah1[2], axh[2], axl[2];
#pragma unroll
    for (int Tt = 0; Tt < 2; ++Tt) {
#pragma unroll
        for (int j = 0; j < 8; ++j) {
            const int k   = 8 * g + j;
            const int kp  = 16 * ((k >> 2) & 1) + 4 * (k >> 3) + (k & 3);
            const int row = 16 * Tt + c;
            ah0[Tt][j] = (_Float16)W_hh0[row * H_ + kp];
            ai1[Tt][j] = (_Float16)W_ih1[row * H_ + kp];
            ah1[Tt][j] = (_Float16)W_hh1[row * H_ + kp];
            const float wx = (k < IN_) ? W_ih0[row * IN_ + k] : 0.f;
            const _Float16 wh = (_Float16)wx;
            axh[Tt][j] = wh;
            axl[Tt][j] = (_Float16)(wx - (float)wh);   // residual for f32 accuracy
        }
    }
    // ---- bias C-inits (C layout: lane(g,c) reg r = unit 16T+4g+r) ----
    f32x4 b0i[2], b1i[2];
#pragma unroll
    for (int Tt = 0; Tt < 2; ++Tt)
#pragma unroll
        for (int r = 0; r < 4; ++r) {
            const int uu = 16 * Tt + 4 * g + r;
            b0i[Tt][r] = b_ih0[uu] + b_hh0[uu];
            b1i[Tt][r] = b_ih1[uu] + b_hh1[uu];
        }
    const f32x4 zf4 = {0.f, 0.f, 0.f, 0.f};

    __shared__ float xlds[4 * 64 * XP_];     // [slot][lane][20] x staging
    __shared__ _Float16 hfin[16][H_];        // final h2 for FC head

    // ---- x staging: lane(g,c) owns timesteps 4g+s (s=0..3) of batch b ----
    float xr[4][IN_];
    const float* xg = x + ((size_t)b * T_ + 4 * g) * IN_;
#pragma unroll
    for (int s = 0; s < 4; ++s)
#pragma unroll
        for (int i = 0; i < IN_; i += 2) {
            const float2 v = *(const float2*)(xg + s * IN_ + i);
            xr[s][i] = v.x; xr[s][i + 1] = v.y;
        }
    xg += CT_ * IN_;

    f16x8 h1f, h2f;
#pragma unroll
    for (int j = 0; j < 8; ++j) { h1f[j] = (_Float16)0.f; h2f[j] = (_Float16)0.f; }

    f32x4 xpc0[CT_], xpc1[CT_];

    // ---- PHASEX: dump x regs -> LDS, prefetch next chunk, xproj via MFMA ----
#define PHASEX(PREFETCH)                                                     \
    {                                                                        \
        _Pragma("unroll")                                                    \
        for (int s_ = 0; s_ < 4; ++s_) {                                     \
            float* dst_ = &xlds[(s_ * 64 + lane) * XP_];                     \
            *(float4*)(dst_)     = make_float4(xr[s_][0], xr[s_][1],         \
                                               xr[s_][2], xr[s_][3]);        \
            *(float4*)(dst_ + 4) = make_float4(xr[s_][4], xr[s_][5],         \
                                               xr[s_][6], xr[s_][7]);        \
            *(float2*)(dst_ + 8) = make_float2(xr[s_][8], xr[s_][9]);        \
        }                                                                    \
        if (PREFETCH) {                                                      \
            _Pragma("unroll")                                                \
            for (int s_ = 0; s_ < 4; ++s_)                                   \
                _Pragma("unroll")                                            \
                for (int i_ = 0; i_ < IN_; i_ += 2) {                        \
                    const float2 v_ = *(const float2*)(xg + s_ * IN_ + i_);  \
                    xr[s_][i_] = v_.x; xr[s_][i_ + 1] = v_.y;                \
                }                                                            \
            xg += CT_ * IN_;                                                 \
        }                                                                    \
        cfence();                                                            \
        _Pragma("unroll")                                                    \
        for (int t_ = 0; t_ < CT_; ++t_) {                                   \
            const float* rp_ = &xlds[((t_ & 3) * 64 + (t_ >> 2) * 16 + c) * XP_]; \
            f16x8 bxh_, bxl_;                                                \
            _Pragma("unroll")                                                \
            for (int j_ = 0; j_ < 8; ++j_) {                                 \
                bxh_[j_] = (_Float16)0.f; bxl_[j_] = (_Float16)0.f;          \
            }                                                                \
            if (g == 0) {                                                    \
                const float4 v0_ = *(const float4*)rp_;                      \
                const float4 v1_ = *(const float4*)(rp_ + 4);                \
                const float xv_[8] = {v0_.x, v0_.y, v0_.z, v0_.w,            \
                                      v1_.x, v1_.y, v1_.z, v1_.w};           \
                _Pragma("unroll")                                            \
                for (int j_ = 0; j_ < 8; ++j_) {                             \
                    const _Float16 hh_ = (_Float16)xv_[j_];                  \
                    bxh_[j_] = hh_;                                          \
                    bxl_[j_] = (_Float16)(xv_[j_] - (float)hh_);             \
                }                                                            \
            } else if (g == 1) {                                             \
                const float2 v2_ = *(const float2*)(rp_ + 8);                \
                const _Float16 ha_ = (_Float16)v2_.x;                        \
                bxh_[0] = ha_; bxl_[0] = (_Float16)(v2_.x - (float)ha_);     \
                const _Float16 hb_ = (_Float16)v2_.y;                        \
                bxh_[1] = hb_; bxl_[1] = (_Float16)(v2_.y - (float)hb_);     \
            }                                                                \
            f32x4 p0_ = MFMA(axh[0], bxh_, b0i[0]);                          \
            f32x4 p1_ = MFMA(axh[1], bxh_, b0i[1]);                          \
            p0_ = MFMA(axh[0], bxl_, p0_);                                   \
            p1_ = MFMA(axh[1], bxl_, p1_);                                   \
            p0_ = MFMA(axl[0], bxh_, p0_);                                   \
            p1_ = MFMA(axl[1], bxh_, p1_);                                   \
            xpc0[t_] = p0_; xpc1[t_] = p1_;                                  \
        }                                                                    \
    }

    // ---- STEP (iteration tau): h1[tau] and h2[tau-1]. All 6 MFMAs
    //      mutually independent (read old h1f/h2f + constant C-inits). ----
#define STEP(RR)                                                             \
    {                                                                        \
        const f32x4 c0_ = MFMA(ah0[0], h1f, xpc0[RR]);                       \
        const f32x4 c1_ = MFMA(ah0[1], h1f, xpc1[RR]);                       \
        const f32x4 d0_ = MFMA(ai1[0], h1f, b1i[0]);                         \
        const f32x4 d1_ = MFMA(ai1[1], h1f, b1i[1]);                         \
        const f32x4 e0_ = MFMA(ah1[0], h2f, zf4);                            \
        const f32x4 e1_ = MFMA(ah1[1], h2f, zf4);                            \
        f16x8 nh1_, nh2_;                                                    \
        _Pragma("unroll")                                                    \
        for (int r_ = 0; r_ < 4; ++r_) {                                     \
            nh1_[r_]     = (_Float16)fmaxf(c0_[r_], 0.f);                    \
            nh1_[4 + r_] = (_Float16)fmaxf(c1_[r_], 0.f);                    \
            nh2_[r_]     = (_Float16)fmaxf(d0_[r_] + e0_[r_], 0.f);          \
            nh2_[4 + r_] = (_Float16)fmaxf(d1_[r_] + e1_[r_], 0.f);          \
        }                                                                    \
        h1f = nh1_; h2f = nh2_;                                              \
    }

    // ---- chunk 0: phase X, prologue tau=0 (h1[0]=relu(xp[0]), h2f=0) ----
    PHASEX(1);
    {
        f16x8 nh1;
#pragma unroll
        for (int r = 0; r < 4; ++r) {
            nh1[r]     = (_Float16)fmaxf(xpc0[0][r], 0.f);
            nh1[4 + r] = (_Float16)fmaxf(xpc1[0][r], 0.f);
        }
        h1f = nh1;   // h2f stays 0 (h2[-1] := 0)
    }
#pragma unroll
    for (int r = 1; r < CT_; ++r) STEP(r);

    // ---- chunks 1..31 ----
#pragma unroll 1
    for (int n = 1; n < NCH; ++n) {
        PHASEX(n < NCH - 1);
#pragma unroll
        for (int r = 0; r < CT_; ++r) STEP(r);
    }

    // ---- epilogue: h2[511] = relu(b1 + W_ih1.h1[511] + W_hh1.h2[510]) ----
    {
        const f32x4 d0 = MFMA(ai1[0], h1f, b1i[0]);
        const f32x4 d1 = MFMA(ai1[1], h1f, b1i[1]);
        const f32x4 e0 = MFMA(ah1[0], h2f, zf4);
        const f32x4 e1 = MFMA(ah1[1], h2f, zf4);
        f16x8 nh2;
#pragma unroll
        for (int r = 0; r < 4; ++r) {
            nh2[r]     = (_Float16)fmaxf(d0[r] + e0[r], 0.f);
            nh2[4 + r] = (_Float16)fmaxf(d1[r] + e1[r], 0.f);
        }
        h2f = nh2;
    }

    // ---- FC head: h2f C-layout -> hfin[c][unit], then 2-3 classes/lane ----
#pragma unroll
    for (int r = 0; r < 4; ++r) {
        hfin[c][4 * g + r]      = h2f[r];
        hfin[c][16 + 4 * g + r] = h2f[4 + r];
    }
    cfence();   // single-wave in-order DS pipe: writes precede reads
    {
        float acc0 = b_fc[g];
        float acc1 = b_fc[g + 4];
        float acc2 = (g == 0) ? b_fc[8] : 0.f;
#pragma unroll
        for (int k = 0; k < H_; ++k) {
            const float hv = (float)hfin[c][k];
            acc0 = fmaf(W_fc[g * H_ + k], hv, acc0);
            acc1 = fmaf(W_fc[(g + 4) * H_ + k], hv, acc1);
            if (g == 0) acc2 = fmaf(W_fc[8 * H_ + k], hv, acc2);
        }
        out[b * NC_ + g]     = acc0;
        out[b * NC_ + g + 4] = acc1;
        if (g == 0) out[b * NC_ + 8] = acc2;
    }
#undef PHASEX
#undef STEP
}

extern "C" void kernel_launch(void* const* d_in, const int* in_sizes, int n_in,
                              void* d_out, int out_size, void* d_ws, size_t ws_size,
                              hipStream_t stream) {
    const float* x     = (const float*)d_in[0];
    const float* W_ih0 = (const float*)d_in[1];
    const float* W_hh0 = (const float*)d_in[2];
    const float* b_ih0 = (const float*)d_in[3];
    const float* b_hh0 = (const float*)d_in[4];
    const float* W_ih1 = (const float*)d_in[5];
    const float* W_hh1 = (const float*)d_in[6];
    const float* b_ih1 = (const float*)d_in[7];
    const float* b_hh1 = (const float*)d_in[8];
    const float* W_fc  = (const float*)d_in[9];
    const float* b_fc  = (const float*)d_in[10];
    float* out = (float*)d_out;

    const int B = in_sizes[0] / (T_ * IN_);   // 4096
    gesture_rnn_kernel<<<dim3(B / 16), dim3(64), 0, stream>>>(
        x, W_ih0, W_hh0, b_ih0, b_hh0, W_ih1, W_hh1, b_ih1, b_hh1,
        W_fc, b_fc, out);
}

// Round 6
// 300.729 us; speedup vs baseline: 1.0410x; 1.0410x over previous
//
#include <hip/hip_runtime.h>

// GestureRNN v14: v13 MFMA core, xproj software-pipelined depth-1 (NO arrays).
// B=4096, T=512, IN=10, H=32, NCLS=9.
//
// v12/v13 post-mortem (220/209us, MfmaUtil ~4.7%, VALUBusy ~11%, both pipes
// ~88% idle): the xpc0/xpc1 per-chunk arrays (128 VGPRs) exceeded the
// allocation (VGPR_Count=176 vs ~280 needed) -> SPILLED TO SCRATCH. Every
// step opened with two scratch loads feeding the first MFMA: ~400-900 cyc
// serialized stall/step == the measured ~450 cyc/iter. Dependency structure
// was irrelevant (v12==v13) because scratch latency dominated.
// v14 deletes the arrays: xproj is computed one step ahead into 2x f32x4
// registers (xp0/xp1), issued AFTER the 6 independent recurrence MFMAs so
// its 3-chain latency hides under the step. Chunk head computes its first
// xp once (short refill, 32x per kernel). ~190 live VGPRs -> no spill.
// Layout conjugation K(k)=16*((k>>2)&1)+4*(k>>3)+(k&3) HW-verified (v12/13).
// Single wave/block, 256 blocks, no barriers.

constexpr int T_  = 512;
constexpr int IN_ = 10;
constexpr int H_  = 32;
constexpr int NC_ = 9;
constexpr int CT_ = 16;        // timesteps per chunk
constexpr int NCH = T_ / CT_;  // 32 chunks
constexpr int XP_ = 20;        // padded floats per (slot,lane) in xlds

typedef _Float16 f16x8 __attribute__((ext_vector_type(8)));
typedef float    f32x4 __attribute__((ext_vector_type(4)));

__device__ __forceinline__ void cfence() { __asm__ volatile("" ::: "memory"); }

__device__ __forceinline__ f32x4 MFMA(f16x8 a, f16x8 b, f32x4 c) {
    return __builtin_amdgcn_mfma_f32_16x16x32_f16(a, b, c, 0, 0, 0);
}

__global__ __launch_bounds__(64, 1)
__attribute__((amdgpu_waves_per_eu(1, 1)))
void gesture_rnn_kernel(
    const float* __restrict__ x,      // [B, T, IN]
    const float* __restrict__ W_ih0,  // [H, IN]
    const float* __restrict__ W_hh0,  // [H, H]
    const float* __restrict__ b_ih0,  // [H]
    const float* __restrict__ b_hh0,  // [H]
    const float* __restrict__ W_ih1,  // [H, H]
    const float* __restrict__ W_hh1,  // [H, H]
    const float* __restrict__ b_ih1,  // [H]
    const float* __restrict__ b_hh1,  // [H]
    const float* __restrict__ W_fc,   // [NC, H]
    const float* __restrict__ b_fc,   // [NC]
    float* __restrict__ out)          // [B, NC]
{
    const int lane = threadIdx.x;     // 0..63
    const int c    = lane & 15;       // batch slot (B/C col, A row)
    const int g    = lane >> 4;       // k-group (A/B), C row-group
    const long b   = (long)blockIdx.x * 16 + c;

    // ---- A-fragments. Lane l: row = l&15, k = (l>>4)*8 + j.
    //      Recurrent matrices use k-order K(k); xproj uses natural k. ----
    f16x8 ah0[2], ai1[2], ah1[2], axh[2], axl[2];
#pragma unroll
    for (int Tt = 0; Tt < 2; ++Tt) {
#pragma unroll
        for (int j = 0; j < 8; ++j) {
            const int k   = 8 * g + j;
            const int kp  = 16 * ((k >> 2) & 1) + 4 * (k >> 3) + (k & 3);
            const int row = 16 * Tt + c;
            ah0[Tt][j] = (_Float16)W_hh0[row * H_ + kp];
            ai1[Tt][j] = (_Float16)W_ih1[row * H_ + kp];
            ah1[Tt][j] = (_Float16)W_hh1[row * H_ + kp];
            const float wx = (k < IN_) ? W_ih0[row * IN_ + k] : 0.f;
            const _Float16 wh = (_Float16)wx;
            axh[Tt][j] = wh;
            axl[Tt][j] = (_Float16)(wx - (float)wh);   // residual for f32 accuracy
        }
    }
    // ---- bias C-inits (C layout: lane(g,c) reg r = unit 16T+4g+r) ----
    f32x4 b0i[2], b1i[2];
#pragma unroll
    for (int Tt = 0; Tt < 2; ++Tt)
#pragma unroll
        for (int r = 0; r < 4; ++r) {
            const int uu = 16 * Tt + 4 * g + r;
            b0i[Tt][r] = b_ih0[uu] + b_hh0[uu];
            b1i[Tt][r] = b_ih1[uu] + b_hh1[uu];
        }
    const f32x4 zf4 = {0.f, 0.f, 0.f, 0.f};

    __shared__ float xlds[4 * 64 * XP_];     // [slot][lane][20] x staging
    __shared__ _Float16 hfin[16][H_];        // final h2 for FC head

    // ---- x staging: lane(g,c) owns timesteps 4g+s (s=0..3) of batch b ----
    float xr[4][IN_];
    const float* xg = x + ((size_t)b * T_ + 4 * g) * IN_;
#pragma unroll
    for (int s = 0; s < 4; ++s)
#pragma unroll
        for (int i = 0; i < IN_; i += 2) {
            const float2 v = *(const float2*)(xg + s * IN_ + i);
            xr[s][i] = v.x; xr[s][i + 1] = v.y;
        }
    xg += CT_ * IN_;

    f16x8 h1f, h2f;
#pragma unroll
    for (int j = 0; j < 8; ++j) { h1f[j] = (_Float16)0.f; h2f[j] = (_Float16)0.f; }

    f32x4 xp0, xp1;      // xproj pipeline registers (8 VGPRs total)

    // ---- DUMP: x regs -> LDS; optionally prefetch next chunk ----
#define DUMP(PREFETCH)                                                       \
    {                                                                        \
        _Pragma("unroll")                                                    \
        for (int s_ = 0; s_ < 4; ++s_) {                                     \
            float* dst_ = &xlds[(s_ * 64 + lane) * XP_];                     \
            *(float4*)(dst_)     = make_float4(xr[s_][0], xr[s_][1],         \
                                               xr[s_][2], xr[s_][3]);        \
            *(float4*)(dst_ + 4) = make_float4(xr[s_][4], xr[s_][5],         \
                                               xr[s_][6], xr[s_][7]);        \
            *(float2*)(dst_ + 8) = make_float2(xr[s_][8], xr[s_][9]);        \
        }                                                                    \
        if (PREFETCH) {                                                      \
            _Pragma("unroll")                                                \
            for (int s_ = 0; s_ < 4; ++s_)                                   \
                _Pragma("unroll")                                            \
                for (int i_ = 0; i_ < IN_; i_ += 2) {                        \
                    const float2 v_ = *(const float2*)(xg + s_ * IN_ + i_);  \
                    xr[s_][i_] = v_.x; xr[s_][i_ + 1] = v_.y;                \
                }                                                            \
            xg += CT_ * IN_;                                                 \
        }                                                                    \
        cfence();                                                            \
    }

    // ---- XPROJ(TT, P0, P1): xp = W_ih0 @ x[TT] + b0 (f32-accurate split) ----
#define XPROJ(TT, P0, P1)                                                    \
    {                                                                        \
        const float* rp_ = &xlds[(((TT) & 3) * 64 + ((TT) >> 2) * 16 + c) * XP_]; \
        f16x8 bxh_, bxl_;                                                    \
        _Pragma("unroll")                                                    \
        for (int j_ = 0; j_ < 8; ++j_) {                                     \
            bxh_[j_] = (_Float16)0.f; bxl_[j_] = (_Float16)0.f;              \
        }                                                                    \
        if (g == 0) {                                                        \
            const float4 v0_ = *(const float4*)rp_;                          \
            const float4 v1_ = *(const float4*)(rp_ + 4);                    \
            const float xv_[8] = {v0_.x, v0_.y, v0_.z, v0_.w,                \
                                  v1_.x, v1_.y, v1_.z, v1_.w};               \
            _Pragma("unroll")                                                \
            for (int j_ = 0; j_ < 8; ++j_) {                                 \
                const _Float16 hh_ = (_Float16)xv_[j_];                      \
                bxh_[j_] = hh_;                                              \
                bxl_[j_] = (_Float16)(xv_[j_] - (float)hh_);                 \
            }                                                                \
        } else if (g == 1) {                                                 \
            const float2 v2_ = *(const float2*)(rp_ + 8);                    \
            const _Float16 ha_ = (_Float16)v2_.x;                            \
            bxh_[0] = ha_; bxl_[0] = (_Float16)(v2_.x - (float)ha_);         \
            const _Float16 hb_ = (_Float16)v2_.y;                            \
            bxh_[1] = hb_; bxl_[1] = (_Float16)(v2_.y - (float)hb_);         \
        }                                                                    \
        P0 = MFMA(axh[0], bxh_, b0i[0]);                                     \
        P1 = MFMA(axh[1], bxh_, b0i[1]);                                     \
        P0 = MFMA(axh[0], bxl_, P0);                                         \
        P1 = MFMA(axh[1], bxl_, P1);                                         \
        P0 = MFMA(axl[0], bxh_, P0);                                         \
        P1 = MFMA(axl[1], bxh_, P1);                                         \
    }

    // ---- STEPP (iteration tau): h1[tau], h2[tau-1]; consumes xp, computes
    //      next xp (for RR+1) AFTER issuing the 6 independent MFMAs. ----
#define STEPP(RR)                                                            \
    {                                                                        \
        const f32x4 c0_ = MFMA(ah0[0], h1f, xp0);                            \
        const f32x4 c1_ = MFMA(ah0[1], h1f, xp1);                            \
        const f32x4 d0_ = MFMA(ai1[0], h1f, b1i[0]);                         \
        const f32x4 d1_ = MFMA(ai1[1], h1f, b1i[1]);                         \
        const f32x4 e0_ = MFMA(ah1[0], h2f, zf4);                            \
        const f32x4 e1_ = MFMA(ah1[1], h2f, zf4);                            \
        f32x4 q0_, q1_;                                                      \
        if ((RR) < CT_ - 1) { XPROJ((RR) + 1, q0_, q1_) }                    \
        f16x8 nh1_, nh2_;                                                    \
        _Pragma("unroll")                                                    \
        for (int r_ = 0; r_ < 4; ++r_) {                                     \
            nh1_[r_]     = (_Float16)fmaxf(c0_[r_], 0.f);                    \
            nh1_[4 + r_] = (_Float16)fmaxf(c1_[r_], 0.f);                    \
            nh2_[r_]     = (_Float16)fmaxf(d0_[r_] + e0_[r_], 0.f);          \
            nh2_[4 + r_] = (_Float16)fmaxf(d1_[r_] + e1_[r_], 0.f);          \
        }                                                                    \
        h1f = nh1_; h2f = nh2_;                                              \
        if ((RR) < CT_ - 1) { xp0 = q0_; xp1 = q1_; }                        \
    }

    // ---- chunk 0: dump, prefetch, xp(0); prologue tau=0 then steps 1..15 ----
    DUMP(1);
    XPROJ(0, xp0, xp1);
    {
        // h1[0] = relu(xp(0)); h2[-1] = 0. Then refill pipeline with xp(1).
        f16x8 nh1;
#pragma unroll
        for (int r = 0; r < 4; ++r) {
            nh1[r]     = (_Float16)fmaxf(xp0[r], 0.f);
            nh1[4 + r] = (_Float16)fmaxf(xp1[r], 0.f);
        }
        h1f = nh1;   // h2f stays 0
        XPROJ(1, xp0, xp1);
    }
#pragma unroll
    for (int r = 1; r < CT_; ++r) STEPP(r);

    // ---- chunks 1..31 ----
#pragma unroll 1
    for (int n = 1; n < NCH; ++n) {
        DUMP(n < NCH - 1);
        XPROJ(0, xp0, xp1);
#pragma unroll
        for (int r = 0; r < CT_; ++r) STEPP(r);
    }

    // ---- epilogue: h2[511] = relu(b1 + W_ih1.h1[511] + W_hh1.h2[510]) ----
    {
        const f32x4 d0 = MFMA(ai1[0], h1f, b1i[0]);
        const f32x4 d1 = MFMA(ai1[1], h1f, b1i[1]);
        const f32x4 e0 = MFMA(ah1[0], h2f, zf4);
        const f32x4 e1 = MFMA(ah1[1], h2f, zf4);
        f16x8 nh2;
#pragma unroll
        for (int r = 0; r < 4; ++r) {
            nh2[r]     = (_Float16)fmaxf(d0[r] + e0[r], 0.f);
            nh2[4 + r] = (_Float16)fmaxf(d1[r] + e1[r], 0.f);
        }
        h2f = nh2;
    }

    // ---- FC head: h2f C-layout -> hfin[c][unit], then 2-3 classes/lane ----
#pragma unroll
    for (int r = 0; r < 4; ++r) {
        hfin[c][4 * g + r]      = h2f[r];
        hfin[c][16 + 4 * g + r] = h2f[4 + r];
    }
    cfence();   // single-wave in-order DS pipe: writes precede reads
    {
        float acc0 = b_fc[g];
        float acc1 = b_fc[g + 4];
        float acc2 = (g == 0) ? b_fc[8] : 0.f;
#pragma unroll
        for (int k = 0; k < H_; ++k) {
            const float hv = (float)hfin[c][k];
            acc0 = fmaf(W_fc[g * H_ + k], hv, acc0);
            acc1 = fmaf(W_fc[(g + 4) * H_ + k], hv, acc1);
            if (g == 0) acc2 = fmaf(W_fc[8 * H_ + k], hv, acc2);
        }
        out[b * NC_ + g]     = acc0;
        out[b * NC_ + g + 4] = acc1;
        if (g == 0) out[b * NC_ + 8] = acc2;
    }
#undef DUMP
#undef XPROJ
#undef STEPP
}

extern "C" void kernel_launch(void* const* d_in, const int* in_sizes, int n_in,
                              void* d_out, int out_size, void* d_ws, size_t ws_size,
                              hipStream_t stream) {
    const float* x     = (const float*)d_in[0];
    const float* W_ih0 = (const float*)d_in[1];
    const float* W_hh0 = (const float*)d_in[2];
    const float* b_ih0 = (const float*)d_in[3];
    const float* b_hh0 = (const float*)d_in[4];
    const float* W_ih1 = (const float*)d_in[5];
    const float* W_hh1 = (const float*)d_in[6];
    const float* b_ih1 = (const float*)d_in[7];
    const float* b_hh1 = (const float*)d_in[8];
    const float* W_fc  = (const float*)d_in[9];
    const float* b_fc  = (const float*)d_in[10];
    float* out = (float*)d_out;

    const int B = in_sizes[0] / (T_ * IN_);   // 4096
    gesture_rnn_kernel<<<dim3(B / 16), dim3(64), 0, stream>>>(
        x, W_ih0, W_hh0, b_ih0, b_hh0, W_ih1, W_hh1, b_ih1, b_hh1,
        W_fc, b_fc, out);
}

// Round 7
// 299.902 us; speedup vs baseline: 1.0438x; 1.0028x over previous
//
#include <hip/hip_runtime.h>

// GestureRNN v15: v14 MFMA core + depth-2 xproj pipeline + double-buffered
// x LDS with mid-chunk staging (no chunk-boundary refill bubble).
// B=4096, T=512, IN=10, H=32, NCLS=9.
//
// v14 post-mortem (199us, MfmaUtil 5%, VALUBusy 12%): no spill (VGPR=116)
// yet flat. Calibration vs v9 (VALU-issue-bound at 82% busy) puts effective
// clock ~0.96 GHz => v14 = ~373 cyc/step. Matches the depth-1 xproj chain:
// ds_read(~120)+unpack(~20)+3 dep MFMAs(~90) produced in step tau-1 and
// consumed by the FIRST MFMA of step tau (~100 cyc of issue in between) ->
// ~230-300 cyc exposed per step. v15: xpA/xpB depth-2 pipeline (production
// to consumption spans TWO steps, ~250 cyc of issue), and the next chunk's
// x tile is staged mid-chunk into the second xlds buffer so steps 14/15
// XPROJ the next chunk's t=0,1 -> no per-chunk serial refill.
// Remaining carried chain: h1f->MFMA->cvt->h1f (~45 cyc) << issue/step.
// Layout conjugation K(k)=16*((k>>2)&1)+4*(k>>3)+(k&3) HW-verified (v12+).
// Single wave/block, 256 blocks, no barriers.

constexpr int T_  = 512;
constexpr int IN_ = 10;
constexpr int H_  = 32;
constexpr int NC_ = 9;
constexpr int CT_ = 16;        // timesteps per chunk
constexpr int NCH = T_ / CT_;  // 32 chunks
constexpr int XP_ = 20;        // padded floats per (slot,lane) in xlds

typedef _Float16 f16x8 __attribute__((ext_vector_type(8)));
typedef float    f32x4 __attribute__((ext_vector_type(4)));

__device__ __forceinline__ void cfence() { __asm__ volatile("" ::: "memory"); }

__device__ __forceinline__ f32x4 MFMA(f16x8 a, f16x8 b, f32x4 c) {
    return __builtin_amdgcn_mfma_f32_16x16x32_f16(a, b, c, 0, 0, 0);
}

__global__ __launch_bounds__(64, 1)
__attribute__((amdgpu_waves_per_eu(1, 1)))
void gesture_rnn_kernel(
    const float* __restrict__ x,      // [B, T, IN]
    const float* __restrict__ W_ih0,  // [H, IN]
    const float* __restrict__ W_hh0,  // [H, H]
    const float* __restrict__ b_ih0,  // [H]
    const float* __restrict__ b_hh0,  // [H]
    const float* __restrict__ W_ih1,  // [H, H]
    const float* __restrict__ W_hh1,  // [H, H]
    const float* __restrict__ b_ih1,  // [H]
    const float* __restrict__ b_hh1,  // [H]
    const float* __restrict__ W_fc,   // [NC, H]
    const float* __restrict__ b_fc,   // [NC]
    float* __restrict__ out)          // [B, NC]
{
    const int lane = threadIdx.x;     // 0..63
    const int c    = lane & 15;       // batch slot (B/C col, A row)
    const int g    = lane >> 4;       // k-group (A/B), C row-group
    const long b   = (long)blockIdx.x * 16 + c;

    // ---- A-fragments. Lane l: row = l&15, k = (l>>4)*8 + j.
    //      Recurrent matrices use k-order K(k); xproj uses natural k. ----
    f16x8 ah0[2], ai1[2], ah1[2], axh[2], axl[2];
#pragma unroll
    for (int Tt = 0; Tt < 2; ++Tt) {
#pragma unroll
        for (int j = 0; j < 8; ++j) {
            const int k   = 8 * g + j;
            const int kp  = 16 * ((k >> 2) & 1) + 4 * (k >> 3) + (k & 3);
            const int row = 16 * Tt + c;
            ah0[Tt][j] = (_Float16)W_hh0[row * H_ + kp];
            ai1[Tt][j] = (_Float16)W_ih1[row * H_ + kp];
            ah1[Tt][j] = (_Float16)W_hh1[row * H_ + kp];
            const float wx = (k < IN_) ? W_ih0[row * IN_ + k] : 0.f;
            const _Float16 wh = (_Float16)wx;
            axh[Tt][j] = wh;
            axl[Tt][j] = (_Float16)(wx - (float)wh);   // residual for f32 accuracy
        }
    }
    // ---- bias C-inits (C layout: lane(g,c) reg r = unit 16T+4g+r) ----
    f32x4 b0i[2], b1i[2];
#pragma unroll
    for (int Tt = 0; Tt < 2; ++Tt)
#pragma unroll
        for (int r = 0; r < 4; ++r) {
            const int uu = 16 * Tt + 4 * g + r;
            b0i[Tt][r] = b_ih0[uu] + b_hh0[uu];
            b1i[Tt][r] = b_ih1[uu] + b_hh1[uu];
        }
    const f32x4 zf4 = {0.f, 0.f, 0.f, 0.f};

    __shared__ float xlds[2][4 * 64 * XP_];  // double-buffered x staging
    __shared__ _Float16 hfin[16][H_];        // final h2 for FC head

    // ---- x staging: lane(g,c) owns timesteps 4g+s (s=0..3) of batch b ----
    float xr[4][IN_];
    const float* xg = x + ((size_t)b * T_ + 4 * g) * IN_;
#pragma unroll
    for (int s = 0; s < 4; ++s)
#pragma unroll
        for (int i = 0; i < IN_; i += 2) {
            const float2 v = *(const float2*)(xg + s * IN_ + i);
            xr[s][i] = v.x; xr[s][i + 1] = v.y;
        }
    xg += CT_ * IN_;

    f16x8 h1f, h2f;
#pragma unroll
    for (int j = 0; j < 8; ++j) { h1f[j] = (_Float16)0.f; h2f[j] = (_Float16)0.f; }

    f32x4 xpA0, xpA1, xpB0, xpB1;   // depth-2 xproj pipeline (16 VGPRs)

    // ---- DUMP(BASE, PREFETCH): x regs -> LDS buffer; prefetch next chunk ----
#define DUMP(BASE, PREFETCH)                                                 \
    {                                                                        \
        _Pragma("unroll")                                                    \
        for (int s_ = 0; s_ < 4; ++s_) {                                     \
            float* dst_ = (BASE) + (s_ * 64 + lane) * XP_;                   \
            *(float4*)(dst_)     = make_float4(xr[s_][0], xr[s_][1],         \
                                               xr[s_][2], xr[s_][3]);        \
            *(float4*)(dst_ + 4) = make_float4(xr[s_][4], xr[s_][5],         \
                                               xr[s_][6], xr[s_][7]);        \
            *(float2*)(dst_ + 8) = make_float2(xr[s_][8], xr[s_][9]);        \
        }                                                                    \
        if (PREFETCH) {                                                      \
            _Pragma("unroll")                                                \
            for (int s_ = 0; s_ < 4; ++s_)                                   \
                _Pragma("unroll")                                            \
                for (int i_ = 0; i_ < IN_; i_ += 2) {                        \
                    const float2 v_ = *(const float2*)(xg + s_ * IN_ + i_);  \
                    xr[s_][i_] = v_.x; xr[s_][i_ + 1] = v_.y;                \
                }                                                            \
            xg += CT_ * IN_;                                                 \
        }                                                                    \
        cfence();                                                            \
    }

    // ---- XPROJ(BASE, TT, P0, P1): xp = W_ih0 @ x[TT] + b0 (f32 split) ----
#define XPROJ(BASE, TT, P0, P1)                                              \
    {                                                                        \
        const float* rp_ = (BASE) +                                          \
            ((((TT) & 3) * 64 + ((TT) >> 2) * 16 + c) * XP_);                \
        f16x8 bxh_, bxl_;                                                    \
        _Pragma("unroll")                                                    \
        for (int j_ = 0; j_ < 8; ++j_) {                                     \
            bxh_[j_] = (_Float16)0.f; bxl_[j_] = (_Float16)0.f;              \
        }                                                                    \
        if (g == 0) {                                                        \
            const float4 v0_ = *(const float4*)rp_;                          \
            const float4 v1_ = *(const float4*)(rp_ + 4);                    \
            const float xv_[8] = {v0_.x, v0_.y, v0_.z, v0_.w,                \
                                  v1_.x, v1_.y, v1_.z, v1_.w};               \
            _Pragma("unroll")                                                \
            for (int j_ = 0; j_ < 8; ++j_) {                                 \
                const _Float16 hh_ = (_Float16)xv_[j_];                      \
                bxh_[j_] = hh_;                                              \
                bxl_[j_] = (_Float16)(xv_[j_] - (float)hh_);                 \
            }                                                                \
        } else if (g == 1) {                                                 \
            const float2 v2_ = *(const float2*)(rp_ + 8);                    \
            const _Float16 ha_ = (_Float16)v2_.x;                            \
            bxh_[0] = ha_; bxl_[0] = (_Float16)(v2_.x - (float)ha_);         \
            const _Float16 hb_ = (_Float16)v2_.y;                            \
            bxh_[1] = hb_; bxl_[1] = (_Float16)(v2_.y - (float)hb_);         \
        }                                                                    \
        P0 = MFMA(axh[0], bxh_, b0i[0]);                                     \
        P1 = MFMA(axh[1], bxh_, b0i[1]);                                     \
        P0 = MFMA(axh[0], bxl_, P0);                                         \
        P1 = MFMA(axh[1], bxl_, P1);                                         \
        P0 = MFMA(axl[0], bxh_, P0);                                         \
        P1 = MFMA(axl[1], bxh_, P1);                                         \
    }

    // ---- STEPP: consumes xpA (= xp(tau)); computes xp(tau+2) into the
    //      pipeline. Invariant on entry: xpA=xp(tau), xpB=xp(tau+1). ----
#define STEPP(RR, DOX, XBASE)                                                \
    {                                                                        \
        const f32x4 c0_ = MFMA(ah0[0], h1f, xpA0);                           \
        const f32x4 c1_ = MFMA(ah0[1], h1f, xpA1);                           \
        const f32x4 d0_ = MFMA(ai1[0], h1f, b1i[0]);                         \
        const f32x4 d1_ = MFMA(ai1[1], h1f, b1i[1]);                         \
        const f32x4 e0_ = MFMA(ah1[0], h2f, zf4);                            \
        const f32x4 e1_ = MFMA(ah1[1], h2f, zf4);                            \
        f32x4 q0_, q1_;                                                      \
        if (DOX) { XPROJ(XBASE, (((RR) + 2) & 15), q0_, q1_) }               \
        f16x8 nh1_, nh2_;                                                    \
        _Pragma("unroll")                                                    \
        for (int r_ = 0; r_ < 4; ++r_) {                                     \
            nh1_[r_]     = (_Float16)fmaxf(c0_[r_], 0.f);                    \
            nh1_[4 + r_] = (_Float16)fmaxf(c1_[r_], 0.f);                    \
            nh2_[r_]     = (_Float16)fmaxf(d0_[r_] + e0_[r_], 0.f);          \
            nh2_[4 + r_] = (_Float16)fmaxf(d1_[r_] + e1_[r_], 0.f);          \
        }                                                                    \
        h1f = nh1_; h2f = nh2_;                                              \
        xpA0 = xpB0; xpA1 = xpB1;                                            \
        if (DOX) { xpB0 = q0_; xpB1 = q1_; }                                 \
    }

    float* bufA = &xlds[0][0];
    float* bufB = &xlds[1][0];

    // ---- chunk 0 prologue: stage chunk0, prefetch chunk1, fill pipeline ----
    DUMP(bufA, 1);
    XPROJ(bufA, 0, xpA0, xpA1);
    XPROJ(bufA, 1, xpB0, xpB1);
    {
        // tau=0: h1[0] = relu(xp(0)); h2[-1] = 0. Advance pipeline.
        f16x8 nh1;
#pragma unroll
        for (int r = 0; r < 4; ++r) {
            nh1[r]     = (_Float16)fmaxf(xpA0[r], 0.f);
            nh1[4 + r] = (_Float16)fmaxf(xpA1[r], 0.f);
        }
        h1f = nh1;   // h2f stays 0
        xpA0 = xpB0; xpA1 = xpB1;
        XPROJ(bufA, 2, xpB0, xpB1);
    }
    // ---- chunk 0 steps 1..15 (mid-chunk: stage chunk1 -> bufB) ----
#pragma unroll
    for (int r = 1; r < 8; ++r) STEPP(r, 1, bufA);
    DUMP(bufB, 1);   // stage chunk1, prefetch chunk2
#pragma unroll
    for (int r = 8; r < 14; ++r) STEPP(r, 1, bufA);
    STEPP(14, 1, bufB);   // XPROJ t=0 of chunk1
    STEPP(15, 1, bufB);   // XPROJ t=1 of chunk1

    // ---- chunks 1..30 ----
    float* cur = bufB;
    float* nxt = bufA;
#pragma unroll 1
    for (int n = 1; n <= 30; ++n) {
#pragma unroll
        for (int r = 0; r < 8; ++r) STEPP(r, 1, cur);
        DUMP(nxt, (n < 30));   // stage chunk n+1, prefetch chunk n+2
#pragma unroll
        for (int r = 8; r < 14; ++r) STEPP(r, 1, cur);
        STEPP(14, 1, nxt);
        STEPP(15, 1, nxt);
        float* tmp = cur; cur = nxt; nxt = tmp;
    }

    // ---- chunk 31 (no staging, no next-chunk XPROJ) ----
#pragma unroll
    for (int r = 0; r < 14; ++r) STEPP(r, 1, cur);
    STEPP(14, 0, cur);
    STEPP(15, 0, cur);

    // ---- epilogue: h2[511] = relu(b1 + W_ih1.h1[511] + W_hh1.h2[510]) ----
    {
        const f32x4 d0 = MFMA(ai1[0], h1f, b1i[0]);
        const f32x4 d1 = MFMA(ai1[1], h1f, b1i[1]);
        const f32x4 e0 = MFMA(ah1[0], h2f, zf4);
        const f32x4 e1 = MFMA(ah1[1], h2f, zf4);
        f16x8 nh2;
#pragma unroll
        for (int r = 0; r < 4; ++r) {
            nh2[r]     = (_Float16)fmaxf(d0[r] + e0[r], 0.f);
            nh2[4 + r] = (_Float16)fmaxf(d1[r] + e1[r], 0.f);
        }
        h2f = nh2;
    }

    // ---- FC head: h2f C-layout -> hfin[c][unit], then 2-3 classes/lane ----
#pragma unroll
    for (int r = 0; r < 4; ++r) {
        hfin[c][4 * g + r]      = h2f[r];
        hfin[c][16 + 4 * g + r] = h2f[4 + r];
    }
    cfence();   // single-wave in-order DS pipe: writes precede reads
    {
        float acc0 = b_fc[g];
        float acc1 = b_fc[g + 4];
        float acc2 = (g == 0) ? b_fc[8] : 0.f;
#pragma unroll
        for (int k = 0; k < H_; ++k) {
            const float hv = (float)hfin[c][k];
            acc0 = fmaf(W_fc[g * H_ + k], hv, acc0);
            acc1 = fmaf(W_fc[(g + 4) * H_ + k], hv, acc1);
            if (g == 0) acc2 = fmaf(W_fc[8 * H_ + k], hv, acc2);
        }
        out[b * NC_ + g]     = acc0;
        out[b * NC_ + g + 4] = acc1;
        if (g == 0) out[b * NC_ + 8] = acc2;
    }
#undef DUMP
#undef XPROJ
#undef STEPP
}

extern "C" void kernel_launch(void* const* d_in, const int* in_sizes, int n_in,
                              void* d_out, int out_size, void* d_ws, size_t ws_size,
                              hipStream_t stream) {
    const float* x     = (const float*)d_in[0];
    const float* W_ih0 = (const float*)d_in[1];
    const float* W_hh0 = (const float*)d_in[2];
    const float* b_ih0 = (const float*)d_in[3];
    const float* b_hh0 = (const float*)d_in[4];
    const float* W_ih1 = (const float*)d_in[5];
    const float* W_hh1 = (const float*)d_in[6];
    const float* b_ih1 = (const float*)d_in[7];
    const float* b_hh1 = (const float*)d_in[8];
    const float* W_fc  = (const float*)d_in[9];
    const float* b_fc  = (const float*)d_in[10];
    float* out = (float*)d_out;

    const int B = in_sizes[0] / (T_ * IN_);   // 4096
    gesture_rnn_kernel<<<dim3(B / 16), dim3(64), 0, stream>>>(
        x, W_ih0, W_hh0, b_ih0, b_hh0, W_ih1, W_hh1, b_ih1, b_hh1,
        W_fc, b_fc, out);
}